// Round 2
// baseline (155.532 us; speedup 1.0000x reference)
//
#include <hip/hip_runtime.h>
#include <hip/hip_bf16.h>

typedef __bf16 bf16_t;
typedef __bf16 bf16x4 __attribute__((ext_vector_type(4)));
typedef __bf16 bf16x8 __attribute__((ext_vector_type(8)));
typedef float f32x4 __attribute__((ext_vector_type(4)));

#define ALPHA 8.3f
#define CPAD 72   // bf16 channel stride (144 B, 16B-aligned, conflict-free reads)
#define NCOL 68   // staged cols (64-q tile + halo + align)

// img: [4][64][256][256] f32, depth: [4][1][256][256] f32,
// weight: [64][64][3][3] f32, bias: [1][64] f32, out: [4][64][254][254] f32

// Repack weight -> bf16 A-fragment order [tap(9)][chunk(2)][mblock(4)][lane(64)][j(8)]
//   oc = mblock*16 + (lane&15), c = chunk*32 + (lane>>4)*8 + j
__global__ void repack_w(const float* __restrict__ w, bf16_t* __restrict__ w2) {
    int idx = blockIdx.x * 256 + threadIdx.x;  // 0..36863
    if (idx >= 9 * 2 * 4 * 64 * 8) return;
    int j     = idx & 7;
    int lane  = (idx >> 3) & 63;
    int m     = (idx >> 9) & 3;
    int chunk = (idx >> 11) & 1;
    int tap   = idx >> 12;
    int oc = m * 16 + (lane & 15);
    int c  = chunk * 32 + (lane >> 4) * 8 + j;
    int kt = tap / 3, lt = tap % 3;
    w2[idx] = (bf16_t)w[((oc * 64 + c) * 3 + kt) * 3 + lt];
}

// Block = 256 thr (4 waves) = (2 p-rows) x (2 oc-halves); wave tile 32oc x 64q.
// R1 lesson: exact-cohort 1024-block grid = lockstep phases, -20% (81 us). Keep
// 2032 blocks (2 staggered generations) so one block's stage hides under
// another's compute.
// R2 change: batch-issue ALL stage loads (20/thr) + hoist ALL 36 depth loads +
// one-tap-ahead w2 prefetch. Turns ~5 serial HBM-latency rounds per stage and
// per-kt L2 stalls into ~1 latency round each. VGPR budget: must stay <=128
// (LDS caps 4 blk/CU = 4 waves/SIMD).
__global__ __launch_bounds__(256, 2) void depthconv_mfma(
    const float* __restrict__ img, const float* __restrict__ depth,
    const bf16_t* __restrict__ w2, const float* __restrict__ bias,
    float* __restrict__ out)
{
    __shared__ bf16_t lds[4 * NCOL * CPAD];  // 39,168 B -> 4 blocks/CU by LDS

    const int tid = threadIdx.x;
    // blk = ppair*16 + (b*4+qt): each (b,qt) stream stays on one XCD (16%8==0)
    const int blk   = blockIdx.x;
    const int ppair = blk >> 4;
    const int r     = blk & 15;
    const int b     = r >> 2;
    const int qt    = r & 3;
    const int p0    = ppair * 2;
    const int q0    = (qt == 3) ? 190 : qt * 64;  // q 190/191 dup-written identically
    const int s0    = (qt == 3) ? 188 : q0;       // staged col start (float4-aligned)

    const float* imgb = img + (size_t)b * 64 * 65536;
    const float* dep  = depth + (size_t)b * 65536;

    const int wv   = tid >> 6;
    const int lane = tid & 63;
    const int pr   = wv >> 1;          // p-row within pair
    const int mh   = wv & 1;           // oc-half (mblocks 2mh, 2mh+1)
    const int n    = lane & 15;
    const int quad = lane >> 4;
    const int prow = p0 + pr;
    const int clb0 = q0 - s0;

    // ---- stage phase 1: ISSUE all global loads (16 main + 4 tail f32x4/thr) ----
    // unit u: cg=u&15 (4-ch group), colg=(u>>4)%17, row=(u>>4)/17
    f32x4 v[4][4];   // [k][ch]
#pragma unroll
    for (int k = 0; k < 4; ++k) {
        const int u = tid + (k << 8);          // 0..1023
        const int cg = u & 15, rest = u >> 4;
        const int colg = rest % 17, row = rest / 17;
        const float* src = imgb + (size_t)(cg * 4) * 65536 + (p0 + row) * 256 + s0 + colg * 4;
#pragma unroll
        for (int ch = 0; ch < 4; ++ch)
            v[k][ch] = *(const f32x4*)(src + (size_t)ch * 65536);
    }
    f32x4 tv[4];
    {
        const int u = 1024 + tid;              // tid<64 -> u 1024..1087
        const int cg = u & 15, rest = u >> 4;
        const int colg = rest % 17, row = rest / 17;
        const float* src = imgb + (size_t)(cg * 4) * 65536 + (p0 + row) * 256 + s0 + colg * 4;
        if (tid < 64) {
#pragma unroll
            for (int ch = 0; ch < 4; ++ch)
                tv[ch] = *(const f32x4*)(src + (size_t)ch * 65536);
        }
    }

    // ---- hoist all depth loads for this block (independent of LDS) ----
    float dre[3][3][4];
#pragma unroll
    for (int kt = 0; kt < 3; ++kt)
#pragma unroll
        for (int lt = 0; lt < 3; ++lt)
#pragma unroll
            for (int i = 0; i < 4; ++i)
                dre[kt][lt][i] = dep[(prow + kt) * 256 + q0 + 16 * i + n + lt];

    // ---- stage phase 2: convert + LDS write (vmcnt drains pipeline-style) ----
#pragma unroll
    for (int k = 0; k < 4; ++k) {
        const int u = tid + (k << 8);
        const int cg = u & 15, rest = u >> 4;
        const int colg = rest % 17, row = rest / 17;
        bf16_t* dst = lds + (size_t)(row * NCOL + colg * 4) * CPAD + cg * 4;
#pragma unroll
        for (int i = 0; i < 4; ++i)
            *(bf16x4*)(dst + i * CPAD) =
                (bf16x4){(bf16_t)v[k][0][i], (bf16_t)v[k][1][i],
                         (bf16_t)v[k][2][i], (bf16_t)v[k][3][i]};
    }
    if (tid < 64) {
        const int u = 1024 + tid;
        const int cg = u & 15, rest = u >> 4;
        const int colg = rest % 17, row = rest / 17;
        bf16_t* dst = lds + (size_t)(row * NCOL + colg * 4) * CPAD + cg * 4;
#pragma unroll
        for (int i = 0; i < 4; ++i)
            *(bf16x4*)(dst + i * CPAD) =
                (bf16x4){(bf16_t)tv[0][i], (bf16_t)tv[1][i],
                         (bf16_t)tv[2][i], (bf16_t)tv[3][i]};
    }

    // ---- depth weights: all 36 exps before the barrier (dc[i] == dre[1][1][i]) ----
    float dwv[3][3][4];
#pragma unroll
    for (int i = 0; i < 4; ++i) {
        const float dc = dre[1][1][i];
#pragma unroll
        for (int kt = 0; kt < 3; ++kt)
#pragma unroll
            for (int lt = 0; lt < 3; ++lt)
                dwv[kt][lt][i] = __expf(-ALPHA * fabsf(dre[kt][lt][i] - dc));
    }

    __syncthreads();

    // ---- compute: 9 taps, one-tap-ahead w2 fragment prefetch ----
    const f32x4 Z = (f32x4){0.f, 0.f, 0.f, 0.f};
    f32x4 acc[2][4];
#pragma unroll
    for (int mm = 0; mm < 2; ++mm)
#pragma unroll
        for (int i = 0; i < 4; ++i) acc[mm][i] = Z;

    const bf16x8* wbase = (const bf16x8*)w2 + (size_t)(mh * 2) * 64 + lane;
    bf16x8 c0 = wbase[0], c1 = wbase[64], c2 = wbase[256], c3 = wbase[320];

#pragma unroll
    for (int tap = 0; tap < 9; ++tap) {
        const int kt = tap / 3, lt = tap % 3;
        const bf16x8 a00 = c0, a01 = c1, a10 = c2, a11 = c3;
        if (tap < 8) {
            const bf16x8* np = wbase + (size_t)(tap + 1) * 512;
            c0 = np[0]; c1 = np[64]; c2 = np[256]; c3 = np[320];
        }
#pragma unroll
        for (int i = 0; i < 4; ++i) {
            const bf16_t* lp = lds
                + (size_t)((pr + kt) * NCOL + clb0 + 16 * i + n + lt) * CPAD + quad * 8;
            const bf16x8 bf0 = *(const bf16x8*)lp;
            const bf16x8 bf1 = *(const bf16x8*)(lp + 32);
            f32x4 P0 = __builtin_amdgcn_mfma_f32_16x16x32_bf16(a00, bf0, Z, 0, 0, 0);
            f32x4 P1 = __builtin_amdgcn_mfma_f32_16x16x32_bf16(a01, bf0, Z, 0, 0, 0);
            P0 = __builtin_amdgcn_mfma_f32_16x16x32_bf16(a10, bf1, P0, 0, 0, 0);
            P1 = __builtin_amdgcn_mfma_f32_16x16x32_bf16(a11, bf1, P1, 0, 0, 0);
            acc[0][i] += dwv[kt][lt][i] * P0;
            acc[1][i] += dwv[kt][lt][i] * P1;
        }
    }

    // epilogue: D[row=quad*4+r2][col=n]; oc = (mh*2+mm)*16 + quad*4 + r2
#pragma unroll
    for (int mm = 0; mm < 2; ++mm) {
#pragma unroll
        for (int r2 = 0; r2 < 4; ++r2) {
            int oc = (mh * 2 + mm) * 16 + quad * 4 + r2;
            float bz = bias[oc];
#pragma unroll
            for (int i = 0; i < 4; ++i) {
                int q = q0 + 16 * i + n;
                out[((size_t)(b * 64 + oc) * 254 + prow) * 254 + q] = acc[mm][i][r2] + bz;
            }
        }
    }
}

extern "C" void kernel_launch(void* const* d_in, const int* in_sizes, int n_in,
                              void* d_out, int out_size, void* d_ws, size_t ws_size,
                              hipStream_t stream) {
    const float* img   = (const float*)d_in[0];
    const float* depth = (const float*)d_in[1];
    const float* w     = (const float*)d_in[2];
    const float* bias  = (const float*)d_in[3];
    bf16_t* w2 = (bf16_t*)d_ws;

    repack_w<<<144, 256, 0, stream>>>(w, w2);
    // 127 p-pairs x 4 b x 4 q-tiles = 2032 blocks, 256 thr (4 waves)
    depthconv_mfma<<<2032, 256, 0, stream>>>(img, depth, w2, bias, (float*)d_out);
}